// Round 1
// 712.540 us; speedup vs baseline: 1.0862x; 1.0862x over previous
//
#include <hip/hip_runtime.h>
#include <cstdint>

#define TT 300   // timesteps
#define TC 75    // TT/4
#define NBATCH 4

typedef float pf2 __attribute__((ext_vector_type(2)));   // packs to v_pk_fma_f32
typedef _Float16 h8t __attribute__((ext_vector_type(8)));  // 4 VGPRs = MFMA f16 A/B frag
typedef float f32x4 __attribute__((ext_vector_type(4)));   // MFMA C/D frag

// PSP + refractory IIR step, exact op order of the reference scan.
__device__ __forceinline__ void psp_step(float z, float& gp, float& hp, float& gr, float& hr, float& s_out) {
    hp = 0.90483741803595957f * (hp + gp);      // a_sr = exp(-1/10)
    gp = 0.90483741803595957f * gp + z;
    hr = 0.36787944117144233f * (hr + gr);      // a_rf = exp(-1)
    gr = 0.36787944117144233f * gr;
    float u = 0.27182818284590452f * hp + (-54.365636569180904f) * hr; // c_sr*hp + c_rf*hr
    float s = (u >= 10.0f) ? 1.0f : 0.0f;
    gr += s;
    s_out = s;
}

// Coalesced R-way partial reduce: zr[p][t] = sum_r z[r*pstride + p*TT + t].
template <int R>
__global__ void k_reduce(const float* __restrict__ z, float* __restrict__ zr,
                         int total4, int pstride) {
    int i = blockIdx.x * 256 + threadIdx.x;
    if (i >= total4) return;
    size_t pos = (size_t)i * 4;
    float4 a = *(const float4*)(z + pos);
#pragma unroll
    for (int r = 1; r < R; ++r) {
        float4 b = *(const float4*)(z + (size_t)r * pstride + pos);
        a.x += b.x; a.y += b.y; a.z += b.z; a.w += b.w;
    }
    *(float4*)(zr + pos) = a;
}

// Per-neuron scan over T with fused R-way partial reduce, 12-step chunks.
template <int R>
__global__ void k_scan_redp(const float* __restrict__ z, float* __restrict__ s,
                            int n_neur, int pstride) {
    int i = blockIdx.x * 64 + threadIdx.x;
    if (i >= n_neur) return;
    const float* zp = z + (size_t)i * TT;
    float* sp = s + (size_t)i * TT;
    float gp = 0.f, hp = 0.f, gr = 0.f, hr = 0.f;
#pragma unroll 1
    for (int c = 0; c < 25; ++c) {
        const float* p = zp + c * 12;
        float4 a0 = *(const float4*)(p);
        float4 a1 = *(const float4*)(p + 4);
        float4 a2 = *(const float4*)(p + 8);
#pragma unroll
        for (int r = 1; r < R; ++r) {
            const float* pr = p + (size_t)r * pstride;
            float4 b0 = *(const float4*)(pr);
            float4 b1 = *(const float4*)(pr + 4);
            float4 b2 = *(const float4*)(pr + 8);
            a0.x += b0.x; a0.y += b0.y; a0.z += b0.z; a0.w += b0.w;
            a1.x += b1.x; a1.y += b1.y; a1.z += b1.z; a1.w += b1.w;
            a2.x += b2.x; a2.y += b2.y; a2.z += b2.z; a2.w += b2.w;
        }
        float4 o0, o1, o2;
        psp_step(a0.x, gp, hp, gr, hr, o0.x);
        psp_step(a0.y, gp, hp, gr, hr, o0.y);
        psp_step(a0.z, gp, hp, gr, hr, o0.z);
        psp_step(a0.w, gp, hp, gr, hr, o0.w);
        psp_step(a1.x, gp, hp, gr, hr, o1.x);
        psp_step(a1.y, gp, hp, gr, hr, o1.y);
        psp_step(a1.z, gp, hp, gr, hr, o1.z);
        psp_step(a1.w, gp, hp, gr, hr, o1.w);
        psp_step(a2.x, gp, hp, gr, hr, o2.x);
        psp_step(a2.y, gp, hp, gr, hr, o2.y);
        psp_step(a2.z, gp, hp, gr, hr, o2.z);
        psp_step(a2.w, gp, hp, gr, hr, o2.w);
        float* q = sp + c * 12;
        *(float4*)(q) = o0;
        *(float4*)(q + 4) = o1;
        *(float4*)(q + 8) = o2;
    }
}

// Fused scan-pool-scan, thread per CONV neuron; quad pool via shfl_xor (exact on 0/1 spikes).
template <int R, int C, int H2, int W2>
__global__ void __launch_bounds__(256) k_spsq(const float* __restrict__ z,
                                              float* __restrict__ s, int pstride) {
    constexpr int H = 2 * H2, W = 2 * W2;
    int i = blockIdx.x * 256 + threadIdx.x;   // grid exact: NBATCH*C*H*W threads
    int q  = i & 3;
    int p  = i >> 2;
    int x2 = p % W2;
    int y2 = (p / W2) % H2;
    int c  = (p / (W2 * H2)) % C;
    int n  = p / (W2 * H2 * C);
    int dy = q >> 1, dx = q & 1;
    const float* zp = z + (((size_t)(n * C + c) * H + 2 * y2 + dy) * W + 2 * x2 + dx) * TT;
    float* so = s + (size_t)p * TT;
    float gp = 0.f, hp = 0.f, gr = 0.f, hr = 0.f;   // conv neuron IIR
    float Gp = 0.f, Hp = 0.f, Gr = 0.f, Hr = 0.f;   // pooled neuron IIR
#pragma unroll 1
    for (int cc = 0; cc < 25; ++cc) {
        const float* pp = zp + cc * 12;
        float4 a0 = *(const float4*)(pp);
        float4 a1 = *(const float4*)(pp + 4);
        float4 a2 = *(const float4*)(pp + 8);
#pragma unroll
        for (int r = 1; r < R; ++r) {
            const float* pr = pp + (size_t)r * pstride;
            float4 b0 = *(const float4*)(pr);
            float4 b1 = *(const float4*)(pr + 4);
            float4 b2 = *(const float4*)(pr + 8);
            a0.x += b0.x; a0.y += b0.y; a0.z += b0.z; a0.w += b0.w;
            a1.x += b1.x; a1.y += b1.y; a1.z += b1.z; a1.w += b1.w;
            a2.x += b2.x; a2.y += b2.y; a2.z += b2.z; a2.w += b2.w;
        }
        float zv[12] = {a0.x, a0.y, a0.z, a0.w, a1.x, a1.y, a1.z, a1.w, a2.x, a2.y, a2.z, a2.w};
        float ov[12];
#pragma unroll
        for (int tt = 0; tt < 12; ++tt) {
            float sq;
            psp_step(zv[tt], gp, hp, gr, hr, sq);
            float t1 = sq + __shfl_xor(sq, 1, 64);
            float pool = t1 + __shfl_xor(t1, 2, 64);
            psp_step(11.0f * pool, Gp, Hp, Gr, Hr, ov[tt]);
        }
        if (q == 0) {
            float* qo = so + cc * 12;
            *(float4*)(qo)     = make_float4(ov[0], ov[1], ov[2],  ov[3]);
            *(float4*)(qo + 4) = make_float4(ov[4], ov[5], ov[6],  ov[7]);
            *(float4*)(qo + 8) = make_float4(ov[8], ov[9], ov[10], ov[11]);
        }
    }
}

// Transpose-pack OIHW weights (COUT, S) -> [s][COUT] so one tap's weights are contiguous.
__global__ void k_pack_w(const float* __restrict__ w, float* __restrict__ wp, int S, int CO, int total) {
    int i = blockIdx.x * 256 + threadIdx.x;
    if (i >= total) return;
    int co = i % CO, s = i / CO;
    wp[i] = w[co * S + s];
}

// Pack 3x3 OIHW conv weights into MFMA A-fragments with f16 hi/lo split:
//   w == hi + lo * 2^-12  (lo stored pre-scaled by 2^12 so it stays in f16 normal range;
//   spikes are exactly {0,1} in f16, so all products are exact; only fp32 accumulation
//   order differs from the reference — same error class as the current passing kernel).
// Layout: [tap 9][kc CIN/32][ct COUT/16][ver 2][lane 64][j 8] halves.
// A-frag convention: lane supplies A[m = lane&15][k = 8*(lane>>4) + j], m = cout, k = ci.
__global__ void k_pack_wmfma(const float* __restrict__ w, _Float16* __restrict__ wm,
                             int CIN, int COUT, int total) {
    int i = blockIdx.x * 256 + threadIdx.x;
    if (i >= total) return;
    int lane = i & 63;
    int r = i >> 6;
    int ver = r & 1; r >>= 1;
    int KC = CIN >> 5, CT = COUT >> 4;
    int ct = r % CT; r /= CT;
    int kc = r % KC;
    int tap = r / KC;
    int ky = tap / 3, kx = tap % 3;
    int co  = ct * 16 + (lane & 15);
    int ci0 = kc * 32 + (lane >> 4) * 8;
    _Float16 out[8];
#pragma unroll
    for (int j = 0; j < 8; ++j) {
        float wf = w[((co * CIN + ci0 + j) * 3 + ky) * 3 + kx];
        _Float16 hi = (_Float16)wf;
        out[j] = ver ? (_Float16)((wf - (float)hi) * 4096.0f) : hi;
    }
    *(h8t*)(wm + (size_t)i * 8) = *(h8t*)out;
}

// 4x4 sum-pool * 11.0 over (N,2,128,128,T) -> z (N,2,32,32,T). Thread = (p, tc), tc fastest.
__global__ void k_pool4(const float* __restrict__ x, float* __restrict__ z) {
    int idx = blockIdx.x * 256 + threadIdx.x;
    if (idx >= NBATCH * 2 * 32 * 32 * TC) return;
    int tc = idx % TC;
    int p  = idx / TC;
    int w  = p % 32;
    int h  = (p / 32) % 32;
    int nc = p / (32 * 32);
    const float* base = x + (((size_t)nc * 128 + h * 4) * 128 + w * 4) * TT + tc * 4;
    float ax = 0.f, ay = 0.f, az = 0.f, aw = 0.f;
#pragma unroll
    for (int i = 0; i < 4; ++i)
#pragma unroll
        for (int j = 0; j < 4; ++j) {
            float4 v = *(const float4*)(base + ((size_t)i * 128 + j) * TT);
            ax += v.x; ay += v.y; az += v.z; aw += v.w;
        }
    float4 o; o.x = 11.0f * ax; o.y = 11.0f * ay; o.z = 11.0f * az; o.w = 11.0f * aw;
    *(float4*)(z + (size_t)p * TT + tc * 4) = o;
}

// LDS-weight conv with packed fp32 FMA (kept for L1 5x5 CIN=2, which is MFMA-awkward).
template <int SPLIT, int CIN, int COUT, int H, int W, int K, int PAD>
__global__ void __launch_bounds__(256) k_conv_lds(const float* __restrict__ s_in,
                                                  const float* __restrict__ wp,
                                                  float* __restrict__ z) {
    constexpr int CBN = COUT / 16;
    constexpr int CIN_SP = CIN / SPLIT;
    constexpr int S_SP = CIN_SP * K * K;
    __shared__ float wlds[S_SP * COUT];
    int nb8 = gridDim.x >> 3;
    int lb  = (blockIdx.x >> 3) + (blockIdx.x & 7) * nb8;
    int sp = (int)(((size_t)lb * 256) / (CBN * NBATCH * H * W * TC));
    {
        const float4* src = (const float4*)(wp + (size_t)sp * S_SP * COUT);
        float4* dst = (float4*)wlds;
        for (int i = threadIdx.x; i < S_SP * COUT / 4; i += 256) dst[i] = src[i];
    }
    __syncthreads();
    int t = lb * 256 + threadIdx.x;
    int tc = t % TC;     t /= TC;
    int cb = t % CBN;    t /= CBN;
    int x  = t % W;      t /= W;
    int y  = t % H;      t /= H;
    int n  = t % NBATCH;
    const float* sb = s_in + ((size_t)n * CIN + sp * CIN_SP) * H * W * TT + tc * 4;
    pf2 acc[4][4][2]; // [cg][c][tt-pair]
#pragma unroll
    for (int a = 0; a < 4; ++a)
#pragma unroll
        for (int b = 0; b < 4; ++b)
#pragma unroll
            for (int d = 0; d < 2; ++d) acc[a][b][d] = (pf2){0.f, 0.f};
#pragma unroll 1
    for (int cl = 0; cl < CIN_SP; ++cl) {
#pragma unroll
        for (int ky = 0; ky < K; ++ky) {
            int yy = y + ky - PAD;
            if (yy < 0 || yy >= H) continue;
#pragma unroll
            for (int kx = 0; kx < K; ++kx) {
                int xx = x + kx - PAD;
                if (xx < 0 || xx >= W) continue;
                float4 v = *(const float4*)(sb + ((size_t)(cl * H + yy) * W + xx) * TT);
                pf2 v01 = {v.x, v.y}, v23 = {v.z, v.w};
                const float* wrow = &wlds[((cl * K + ky) * K + kx) * COUT + cb * 16];
#pragma unroll
                for (int cg = 0; cg < 4; ++cg) {
                    float4 wv = *(const float4*)(wrow + cg * 4);
                    float wa[4] = {wv.x, wv.y, wv.z, wv.w};
#pragma unroll
                    for (int c = 0; c < 4; ++c) {
                        pf2 w2 = {wa[c], wa[c]};
                        acc[cg][c][0] = __builtin_elementwise_fma(w2, v01, acc[cg][c][0]);
                        acc[cg][c][1] = __builtin_elementwise_fma(w2, v23, acc[cg][c][1]);
                    }
                }
            }
        }
    }
    float* zb = z + (((size_t)(sp * NBATCH + n) * COUT + cb * 16) * H * W + (size_t)y * W + x) * TT + tc * 4;
#pragma unroll
    for (int cg = 0; cg < 4; ++cg)
#pragma unroll
        for (int c = 0; c < 4; ++c) {
            float4 o;
            o.x = acc[cg][c][0].x; o.y = acc[cg][c][0].y;
            o.z = acc[cg][c][1].x; o.w = acc[cg][c][1].y;
            *(float4*)(zb + (size_t)(cg * 4 + c) * H * W * TT) = o;
        }
}

// MFMA 3x3 conv (pad 1): spikes {0,1} exact in f16, weights f16 hi/lo split.
// Block = (n, y, tc): stages rows y-1..y+1, all x (+zero pad cols), 16 t, all ci into LDS
// as f16 with an XOR chunk swizzle; 4 waves each compute W/4 output columns x all couts
// via v_mfma_f32_16x16x32_f16 (A = weights [cout x ci], B = spikes [ci x t]).
// C/D layout (HW-verified): col = lane&15 (= t), row = (lane>>4)*4 + reg (= cout).
template <int CIN, int COUT, int H, int W>
__global__ void __launch_bounds__(256, 2) k_conv_mfma(const float* __restrict__ s_in,
                                                      const _Float16* __restrict__ wm,
                                                      float* __restrict__ z) {
    constexpr int NT = 19;          // ceil(300/16)
    constexpr int KC = CIN / 32;    // K-chunks (of 32 ci) per tap
    constexpr int CH = CIN / 8;     // 16B chunks per t in LDS
    constexpr int XL = W + 2;       // staged x columns (with zero pad)
    constexpr int CT = COUT / 16;   // cout tiles
    constexpr int XPW = W / 4;      // output x per wave
    __shared__ _Float16 lds[3 * XL * 16 * CIN];

    int bid = blockIdx.x;
    int tc = bid % NT;
    int y  = (bid / NT) % H;
    int n  = bid / (NT * H);
    int tid = threadIdx.x;

    // ---- stage: f32 spikes -> f16 LDS, zero-filled at x/y borders and t>=300 tail.
    // item i = ((row*XL + xc)*CH + c)*16 + t  (t fastest -> coalesced 64B per 16 lanes).
    constexpr int TOT = 3 * XL * CH * 16;
    for (int i = tid; i < TOT; i += 256) {
        int t   = i & 15;
        int c   = (i >> 4) % CH;
        int xc  = ((i >> 4) / CH) % XL;
        int row = ((i >> 4) / CH) / XL;
        int tg = tc * 16 + t;
        int xi = xc - 1;
        int yi = y + row - 1;
        float v[8] = {0.f, 0.f, 0.f, 0.f, 0.f, 0.f, 0.f, 0.f};
        if (xi >= 0 && xi < W && yi >= 0 && yi < H && tg < TT) {
            const float* p = s_in + (((size_t)(n * CIN + c * 8) * H + yi) * W + xi) * TT + tg;
#pragma unroll
            for (int j = 0; j < 8; ++j) v[j] = p[(size_t)j * H * W * TT];
        }
        h8t hv;
#pragma unroll
        for (int j = 0; j < 8; ++j) hv[j] = (_Float16)v[j];
        int swz = (CIN == 32) ? ((t >> 1) & 3) : (t & 7);   // bank-conflict-free b128 chunks
        int off = ((row * XL + xc) * 16 + t) * CIN + ((c ^ swz) << 3);
        *(h8t*)(lds + off) = hv;
    }
    __syncthreads();

    // ---- compute
    int lane = tid & 63;
    int wv   = tid >> 6;
    int tl   = lane & 15;
    int hi   = lane >> 4;
    f32x4 acc_h[XPW][CT], acc_l[XPW][CT];
#pragma unroll
    for (int a = 0; a < XPW; ++a)
#pragma unroll
        for (int b = 0; b < CT; ++b) {
            acc_h[a][b] = (f32x4){0.f, 0.f, 0.f, 0.f};
            acc_l[a][b] = (f32x4){0.f, 0.f, 0.f, 0.f};
        }
    const h8t* wmv = (const h8t*)wm;
    int swz = (CIN == 32) ? ((tl >> 1) & 3) : (tl & 7);
#pragma unroll
    for (int ky = 0; ky < 3; ++ky) {
#pragma unroll
        for (int kx = 0; kx < 3; ++kx) {
            int tap = ky * 3 + kx;
#pragma unroll
            for (int kc = 0; kc < KC; ++kc) {
                h8t bf[XPW];   // B-frag: lane supplies B[k = 8*hi + j][n = tl]
#pragma unroll
                for (int xi = 0; xi < XPW; ++xi) {
                    int x = wv * XPW + xi;
                    int c = kc * 4 + hi;
                    int off = ((ky * XL + (x + kx)) * 16 + tl) * CIN + ((c ^ swz) << 3);
                    bf[xi] = *(const h8t*)(lds + off);
                }
#pragma unroll
                for (int ct = 0; ct < CT; ++ct) {
                    size_t wbase = ((size_t)(tap * KC + kc) * CT + ct) * 2;
                    h8t ah = wmv[(wbase + 0) * 64 + lane];
                    h8t al = wmv[(wbase + 1) * 64 + lane];
#pragma unroll
                    for (int xi = 0; xi < XPW; ++xi) {
                        acc_h[xi][ct] = __builtin_amdgcn_mfma_f32_16x16x32_f16(ah, bf[xi], acc_h[xi][ct], 0, 0, 0);
                        acc_l[xi][ct] = __builtin_amdgcn_mfma_f32_16x16x32_f16(al, bf[xi], acc_l[xi][ct], 0, 0, 0);
                    }
                }
            }
        }
    }
    // ---- store: u = acc_hi + acc_lo * 2^-12; t = lane&15 (coalesced), co via regs.
    int tg = tc * 16 + tl;
    bool tv = tg < TT;
#pragma unroll
    for (int xi = 0; xi < XPW; ++xi) {
        int x = wv * XPW + xi;
#pragma unroll
        for (int ct = 0; ct < CT; ++ct) {
#pragma unroll
            for (int r = 0; r < 4; ++r) {
                int co = ct * 16 + hi * 4 + r;
                if (tv) z[(((size_t)(n * COUT + co) * H + y) * W + x) * TT + tg]
                        = acc_h[xi][ct][r] + acc_l[xi][ct][r] * 2.44140625e-4f;
            }
        }
    }
}

// FC with f-split, packed fp32 FMA over the t dimension (same chain order per output).
template <int OUT, int FIN, int OPER, int FSPLIT>
__global__ void k_fc_a(const float* __restrict__ s, const float* __restrict__ wgt,
                       float* __restrict__ z) {
    constexpr int OG = OUT / OPER, FCH = FIN / FSPLIT;
    int idx = blockIdx.x * 256 + threadIdx.x;
    if (idx >= NBATCH * OG * TC * FSPLIT) return;
    int tc = idx % TC;
    int og = (idx / TC) % OG;
    int n  = (idx / (TC * OG)) % NBATCH;
    int sp = idx / (TC * OG * NBATCH);
    const float* sb = s + (size_t)n * FIN * TT + (size_t)sp * FCH * TT + tc * 4;
    const float* wb = wgt + (size_t)sp * FCH;
    pf2 acc[OPER][2];
#pragma unroll
    for (int k = 0; k < OPER; ++k) { acc[k][0] = (pf2){0.f, 0.f}; acc[k][1] = (pf2){0.f, 0.f}; }
#pragma unroll 2
    for (int f = 0; f < FCH; f += 4) {
        float4 s0 = *(const float4*)(sb + (size_t)(f + 0) * TT);
        float4 s1 = *(const float4*)(sb + (size_t)(f + 1) * TT);
        float4 s2 = *(const float4*)(sb + (size_t)(f + 2) * TT);
        float4 s3 = *(const float4*)(sb + (size_t)(f + 3) * TT);
        pf2 s0a = {s0.x, s0.y}, s0b = {s0.z, s0.w};
        pf2 s1a = {s1.x, s1.y}, s1b = {s1.z, s1.w};
        pf2 s2a = {s2.x, s2.y}, s2b = {s2.z, s2.w};
        pf2 s3a = {s3.x, s3.y}, s3b = {s3.z, s3.w};
#pragma unroll
        for (int k = 0; k < OPER; ++k) {
            float4 wv = *(const float4*)(wb + (size_t)(og * OPER + k) * FIN + f);
            pf2 wx = {wv.x, wv.x}, wy = {wv.y, wv.y}, wz = {wv.z, wv.z}, ww = {wv.w, wv.w};
            pf2 a0 = acc[k][0], a1 = acc[k][1];
            a0 = __builtin_elementwise_fma(wx, s0a, a0);
            a0 = __builtin_elementwise_fma(wy, s1a, a0);
            a0 = __builtin_elementwise_fma(wz, s2a, a0);
            a0 = __builtin_elementwise_fma(ww, s3a, a0);
            a1 = __builtin_elementwise_fma(wx, s0b, a1);
            a1 = __builtin_elementwise_fma(wy, s1b, a1);
            a1 = __builtin_elementwise_fma(wz, s2b, a1);
            a1 = __builtin_elementwise_fma(ww, s3b, a1);
            acc[k][0] = a0; acc[k][1] = a1;
        }
    }
#pragma unroll
    for (int k = 0; k < OPER; ++k) {
        float4 o;
        o.x = acc[k][0].x; o.y = acc[k][0].y; o.z = acc[k][1].x; o.w = acc[k][1].y;
        *(float4*)(z + ((size_t)sp * NBATCH * OUT + (size_t)n * OUT + og * OPER + k) * TT + tc * 4) = o;
    }
}

extern "C" void kernel_launch(void* const* d_in, const int* in_sizes, int n_in,
                              void* d_out, int out_size, void* d_ws, size_t ws_size,
                              hipStream_t stream) {
    const float* s_in = (const float*)d_in[0]; // (4,2,128,128,300)
    const float* w1   = (const float*)d_in[1]; // (32,2,5,5)
    const float* w2   = (const float*)d_in[2]; // (64,32,3,3)
    const float* w3   = (const float*)d_in[3]; // (64,64,3,3)
    const float* w4a  = (const float*)d_in[4]; // (256,4096)
    const float* w4b  = (const float*)d_in[5]; // (11,256)
    float* out = (float*)d_out;                // (4,11,300)

    // Workspace (floats): Z 39,321,600 | Sb 9,830,400 | packed weights (same 56,896-float
    // footprint as before: w1p 1600 f | wm2 36,864 h = 18,432 f | wm3 73,728 h = 36,864 f).
    float* Z  = (float*)d_ws;
    float* Sb = Z + 39321600;
    float* WP = Sb + 9830400;
    float* w1p = WP;                                     // 50*32 = 1600 floats
    _Float16* wm2 = (_Float16*)(WP + 1600);              // L3 MFMA frags
    _Float16* wm3 = (_Float16*)(WP + 1600 + 18432);      // L5 MFMA frags

    auto g = [](int n) { return (n + 255) / 256; };
    auto g64 = [](int n) { return (n + 63) / 64; };

    k_pack_w<<<g(1600), 256, 0, stream>>>(w1, w1p, 50, 32, 1600);
    k_pack_wmfma<<<g(4608), 256, 0, stream>>>(w2, wm2, 32, 64, 4608);
    k_pack_wmfma<<<g(9216), 256, 0, stream>>>(w3, wm3, 64, 64, 9216);

    // L0: 4x4 pool + psp -> s0 (4,2,32,32,300) @ Sb
    k_pool4<<<g(614400), 256, 0, stream>>>(s_in, Z);
    k_scan_redp<1><<<g64(8192), 64, 0, stream>>>(Z, Sb, 8192, 0);

    // L1 conv 5x5 (2->32, 32x32) on VALU path: z1 (39.3M) @ Z. 2400 blocks exact.
    k_conv_lds<1, 2, 32, 32, 32, 5, 2><<<2400, 256, 0, stream>>>(Sb, w1p, Z);
    // L1 psp + 2x2 pool + L2 psp -> s2 (4,32,16,16,300) @ Sb. 512 blocks.
    k_spsq<1, 32, 16, 16><<<512, 256, 0, stream>>>(Z, Sb, 0);

    // L3 conv 3x3 (32->64, 16x16) MFMA: single-copy z3 (19.66M) @ Z. grid = 4*16*19.
    k_conv_mfma<32, 64, 16, 16><<<1216, 256, 0, stream>>>(Sb, wm2, Z);
    // L3 psp + 2x2 pool + L4 psp -> s4 (4,64,8,8,300) @ Sb. 256 blocks (no split now).
    k_spsq<1, 64, 8, 8><<<256, 256, 0, stream>>>(Z, Sb, 0);

    // L5 conv 3x3 (64->64, 8x8) MFMA: single-copy z5 (4.92M) @ Z. grid = 4*8*19.
    k_conv_mfma<64, 64, 8, 8><<<608, 256, 0, stream>>>(Sb, wm3, Z);
    // psp scan -> s5 @ Sb (16384 neurons, no partials to reduce)
    k_scan_redp<1><<<g64(16384), 64, 0, stream>>>(Z, Sb, 16384, 0);

    // L6: fc 4096->256, 16-way f-split: z6 (16 x 307200) @ Z. 600 blocks.
    k_fc_a<256, 4096, 8, 16><<<600, 256, 0, stream>>>(Sb, w4a, Z);
    k_reduce<16><<<g(76800), 256, 0, stream>>>(Z, Z + 4915200, 76800, 307200);
    k_scan_redp<1><<<g64(1024), 64, 0, stream>>>(Z + 4915200, Sb, 1024, 0);

    // L7: fc 256->11 + psp -> out
    k_fc_a<11, 256, 1, 1><<<g(3300), 256, 0, stream>>>(Sb, w4b, Z);
    k_scan_redp<1><<<1, 64, 0, stream>>>(Z, out, 44, 0);
}

// Round 2
// 652.535 us; speedup vs baseline: 1.1860x; 1.0920x over previous
//
#include <hip/hip_runtime.h>
#include <cstdint>

#define TT 300   // timesteps
#define TC 75    // TT/4
#define NBATCH 4

typedef float pf2 __attribute__((ext_vector_type(2)));   // packs to v_pk_fma_f32
typedef _Float16 h8t __attribute__((ext_vector_type(8)));  // 4 VGPRs = MFMA f16 A/B frag
typedef float f32x4 __attribute__((ext_vector_type(4)));   // MFMA C/D frag

// PSP + refractory IIR step, exact op order of the reference scan.
__device__ __forceinline__ void psp_step(float z, float& gp, float& hp, float& gr, float& hr, float& s_out) {
    hp = 0.90483741803595957f * (hp + gp);      // a_sr = exp(-1/10)
    gp = 0.90483741803595957f * gp + z;
    hr = 0.36787944117144233f * (hr + gr);      // a_rf = exp(-1)
    gr = 0.36787944117144233f * gr;
    float u = 0.27182818284590452f * hp + (-54.365636569180904f) * hr; // c_sr*hp + c_rf*hr
    float s = (u >= 10.0f) ? 1.0f : 0.0f;
    gr += s;
    s_out = s;
}

// Coalesced R-way partial reduce: zr[p][t] = sum_r z[r*pstride + p*TT + t].
template <int R>
__global__ void k_reduce(const float* __restrict__ z, float* __restrict__ zr,
                         int total4, int pstride) {
    int i = blockIdx.x * 256 + threadIdx.x;
    if (i >= total4) return;
    size_t pos = (size_t)i * 4;
    float4 a = *(const float4*)(z + pos);
#pragma unroll
    for (int r = 1; r < R; ++r) {
        float4 b = *(const float4*)(z + (size_t)r * pstride + pos);
        a.x += b.x; a.y += b.y; a.z += b.z; a.w += b.w;
    }
    *(float4*)(zr + pos) = a;
}

// Per-neuron scan over T with fused R-way partial reduce, 12-step chunks.
template <int R>
__global__ void k_scan_redp(const float* __restrict__ z, float* __restrict__ s,
                            int n_neur, int pstride) {
    int i = blockIdx.x * 64 + threadIdx.x;
    if (i >= n_neur) return;
    const float* zp = z + (size_t)i * TT;
    float* sp = s + (size_t)i * TT;
    float gp = 0.f, hp = 0.f, gr = 0.f, hr = 0.f;
#pragma unroll 1
    for (int c = 0; c < 25; ++c) {
        const float* p = zp + c * 12;
        float4 a0 = *(const float4*)(p);
        float4 a1 = *(const float4*)(p + 4);
        float4 a2 = *(const float4*)(p + 8);
#pragma unroll
        for (int r = 1; r < R; ++r) {
            const float* pr = p + (size_t)r * pstride;
            float4 b0 = *(const float4*)(pr);
            float4 b1 = *(const float4*)(pr + 4);
            float4 b2 = *(const float4*)(pr + 8);
            a0.x += b0.x; a0.y += b0.y; a0.z += b0.z; a0.w += b0.w;
            a1.x += b1.x; a1.y += b1.y; a1.z += b1.z; a1.w += b1.w;
            a2.x += b2.x; a2.y += b2.y; a2.z += b2.z; a2.w += b2.w;
        }
        float4 o0, o1, o2;
        psp_step(a0.x, gp, hp, gr, hr, o0.x);
        psp_step(a0.y, gp, hp, gr, hr, o0.y);
        psp_step(a0.z, gp, hp, gr, hr, o0.z);
        psp_step(a0.w, gp, hp, gr, hr, o0.w);
        psp_step(a1.x, gp, hp, gr, hr, o1.x);
        psp_step(a1.y, gp, hp, gr, hr, o1.y);
        psp_step(a1.z, gp, hp, gr, hr, o1.z);
        psp_step(a1.w, gp, hp, gr, hr, o1.w);
        psp_step(a2.x, gp, hp, gr, hr, o2.x);
        psp_step(a2.y, gp, hp, gr, hr, o2.y);
        psp_step(a2.z, gp, hp, gr, hr, o2.z);
        psp_step(a2.w, gp, hp, gr, hr, o2.w);
        float* q = sp + c * 12;
        *(float4*)(q) = o0;
        *(float4*)(q + 4) = o1;
        *(float4*)(q + 8) = o2;
    }
}

// Scan variant that writes ONLY a f16 [n][t][f] spike tensor (for the MFMA FC).
// Per t, a wave's 64 lanes are 64 consecutive f -> 128B segments (coalesced enough;
// total payload is only 9.8 MB written once).
template <int FIN>
__global__ void k_scan_f16(const float* __restrict__ z, _Float16* __restrict__ s16,
                           int n_neur) {
    int i = blockIdx.x * 64 + threadIdx.x;
    if (i >= n_neur) return;
    int n = i / FIN, f = i % FIN;
    const float* zp = z + (size_t)i * TT;
    _Float16* sp = s16 + (size_t)n * TT * FIN + f;
    float gp = 0.f, hp = 0.f, gr = 0.f, hr = 0.f;
#pragma unroll 1
    for (int c = 0; c < 25; ++c) {
        const float* p = zp + c * 12;
        float4 a0 = *(const float4*)(p);
        float4 a1 = *(const float4*)(p + 4);
        float4 a2 = *(const float4*)(p + 8);
        float zv[12] = {a0.x, a0.y, a0.z, a0.w, a1.x, a1.y, a1.z, a1.w, a2.x, a2.y, a2.z, a2.w};
#pragma unroll
        for (int tt = 0; tt < 12; ++tt) {
            float o;
            psp_step(zv[tt], gp, hp, gr, hr, o);
            sp[(size_t)(c * 12 + tt) * FIN] = (_Float16)o;
        }
    }
}

// Fused scan-pool-scan, thread per CONV neuron; quad pool via shfl_xor (exact on 0/1 spikes).
template <int R, int C, int H2, int W2>
__global__ void __launch_bounds__(256) k_spsq(const float* __restrict__ z,
                                              float* __restrict__ s, int pstride) {
    constexpr int H = 2 * H2, W = 2 * W2;
    int i = blockIdx.x * 256 + threadIdx.x;   // grid exact: NBATCH*C*H*W threads
    int q  = i & 3;
    int p  = i >> 2;
    int x2 = p % W2;
    int y2 = (p / W2) % H2;
    int c  = (p / (W2 * H2)) % C;
    int n  = p / (W2 * H2 * C);
    int dy = q >> 1, dx = q & 1;
    const float* zp = z + (((size_t)(n * C + c) * H + 2 * y2 + dy) * W + 2 * x2 + dx) * TT;
    float* so = s + (size_t)p * TT;
    float gp = 0.f, hp = 0.f, gr = 0.f, hr = 0.f;   // conv neuron IIR
    float Gp = 0.f, Hp = 0.f, Gr = 0.f, Hr = 0.f;   // pooled neuron IIR
#pragma unroll 1
    for (int cc = 0; cc < 25; ++cc) {
        const float* pp = zp + cc * 12;
        float4 a0 = *(const float4*)(pp);
        float4 a1 = *(const float4*)(pp + 4);
        float4 a2 = *(const float4*)(pp + 8);
#pragma unroll
        for (int r = 1; r < R; ++r) {
            const float* pr = pp + (size_t)r * pstride;
            float4 b0 = *(const float4*)(pr);
            float4 b1 = *(const float4*)(pr + 4);
            float4 b2 = *(const float4*)(pr + 8);
            a0.x += b0.x; a0.y += b0.y; a0.z += b0.z; a0.w += b0.w;
            a1.x += b1.x; a1.y += b1.y; a1.z += b1.z; a1.w += b1.w;
            a2.x += b2.x; a2.y += b2.y; a2.z += b2.z; a2.w += b2.w;
        }
        float zv[12] = {a0.x, a0.y, a0.z, a0.w, a1.x, a1.y, a1.z, a1.w, a2.x, a2.y, a2.z, a2.w};
        float ov[12];
#pragma unroll
        for (int tt = 0; tt < 12; ++tt) {
            float sq;
            psp_step(zv[tt], gp, hp, gr, hr, sq);
            float t1 = sq + __shfl_xor(sq, 1, 64);
            float pool = t1 + __shfl_xor(t1, 2, 64);
            psp_step(11.0f * pool, Gp, Hp, Gr, Hr, ov[tt]);
        }
        if (q == 0) {
            float* qo = so + cc * 12;
            *(float4*)(qo)     = make_float4(ov[0], ov[1], ov[2],  ov[3]);
            *(float4*)(qo + 4) = make_float4(ov[4], ov[5], ov[6],  ov[7]);
            *(float4*)(qo + 8) = make_float4(ov[8], ov[9], ov[10], ov[11]);
        }
    }
}

// Transpose-pack OIHW weights (COUT, S) -> [s][COUT] so one tap's weights are contiguous.
__global__ void k_pack_w(const float* __restrict__ w, float* __restrict__ wp, int S, int CO, int total) {
    int i = blockIdx.x * 256 + threadIdx.x;
    if (i >= total) return;
    int co = i % CO, s = i / CO;
    wp[i] = w[co * S + s];
}

// Pack 3x3 OIHW conv weights into MFMA A-fragments with f16 hi/lo split:
//   w == hi + lo * 2^-12  (lo pre-scaled by 2^12; spikes are {0,1} so products exact).
// Layout: [tap 9][kc CIN/32][ct COUT/16][ver 2][lane 64][j 8] halves.
// A-frag convention: lane supplies A[m = lane&15][k = 8*(lane>>4) + j], m = cout, k = ci.
__global__ void k_pack_wmfma(const float* __restrict__ w, _Float16* __restrict__ wm,
                             int CIN, int COUT, int total) {
    int i = blockIdx.x * 256 + threadIdx.x;
    if (i >= total) return;
    int lane = i & 63;
    int r = i >> 6;
    int ver = r & 1; r >>= 1;
    int KC = CIN >> 5, CT = COUT >> 4;
    int ct = r % CT; r /= CT;
    int kc = r % KC;
    int tap = r / KC;
    int ky = tap / 3, kx = tap % 3;
    int co  = ct * 16 + (lane & 15);
    int ci0 = kc * 32 + (lane >> 4) * 8;
    _Float16 out[8];
#pragma unroll
    for (int j = 0; j < 8; ++j) {
        float wf = w[((co * CIN + ci0 + j) * 3 + ky) * 3 + kx];
        _Float16 hi = (_Float16)wf;
        out[j] = ver ? (_Float16)((wf - (float)hi) * 4096.0f) : hi;
    }
    *(h8t*)(wm + (size_t)i * 8) = *(h8t*)out;
}

// Pack FC weights (COUT, FIN) row-major into MFMA A-fragments, hi/lo split.
// Layout: [kg FIN/32][ct COUT/16][ver 2][lane 64][j 8] halves.
__global__ void k_pack_wfc(const float* __restrict__ w, _Float16* __restrict__ wm,
                           int FIN, int COUT, int total) {
    int i = blockIdx.x * 256 + threadIdx.x;
    if (i >= total) return;
    int lane = i & 63;
    int r = i >> 6;
    int ver = r & 1; r >>= 1;
    int CT = COUT >> 4;
    int ct = r % CT;
    int kg = r / CT;
    int co = ct * 16 + (lane & 15);
    int f0 = kg * 32 + (lane >> 4) * 8;
    _Float16 out[8];
#pragma unroll
    for (int j = 0; j < 8; ++j) {
        float wf = w[(size_t)co * FIN + f0 + j];
        _Float16 hi = (_Float16)wf;
        out[j] = ver ? (_Float16)((wf - (float)hi) * 4096.0f) : hi;
    }
    *(h8t*)(wm + (size_t)i * 8) = *(h8t*)out;
}

// 4x4 sum-pool * 11.0 over (N,2,128,128,T) -> z (N,2,32,32,T). Thread = (p, tc), tc fastest.
__global__ void k_pool4(const float* __restrict__ x, float* __restrict__ z) {
    int idx = blockIdx.x * 256 + threadIdx.x;
    if (idx >= NBATCH * 2 * 32 * 32 * TC) return;
    int tc = idx % TC;
    int p  = idx / TC;
    int w  = p % 32;
    int h  = (p / 32) % 32;
    int nc = p / (32 * 32);
    const float* base = x + (((size_t)nc * 128 + h * 4) * 128 + w * 4) * TT + tc * 4;
    float ax = 0.f, ay = 0.f, az = 0.f, aw = 0.f;
#pragma unroll
    for (int i = 0; i < 4; ++i)
#pragma unroll
        for (int j = 0; j < 4; ++j) {
            float4 v = *(const float4*)(base + ((size_t)i * 128 + j) * TT);
            ax += v.x; ay += v.y; az += v.z; aw += v.w;
        }
    float4 o; o.x = 11.0f * ax; o.y = 11.0f * ay; o.z = 11.0f * az; o.w = 11.0f * aw;
    *(float4*)(z + (size_t)p * TT + tc * 4) = o;
}

// LDS-weight conv with packed fp32 FMA (kept for L1 5x5 CIN=2, which is MFMA-awkward).
template <int SPLIT, int CIN, int COUT, int H, int W, int K, int PAD>
__global__ void __launch_bounds__(256) k_conv_lds(const float* __restrict__ s_in,
                                                  const float* __restrict__ wp,
                                                  float* __restrict__ z) {
    constexpr int CBN = COUT / 16;
    constexpr int CIN_SP = CIN / SPLIT;
    constexpr int S_SP = CIN_SP * K * K;
    __shared__ float wlds[S_SP * COUT];
    int nb8 = gridDim.x >> 3;
    int lb  = (blockIdx.x >> 3) + (blockIdx.x & 7) * nb8;
    int sp = (int)(((size_t)lb * 256) / (CBN * NBATCH * H * W * TC));
    {
        const float4* src = (const float4*)(wp + (size_t)sp * S_SP * COUT);
        float4* dst = (float4*)wlds;
        for (int i = threadIdx.x; i < S_SP * COUT / 4; i += 256) dst[i] = src[i];
    }
    __syncthreads();
    int t = lb * 256 + threadIdx.x;
    int tc = t % TC;     t /= TC;
    int cb = t % CBN;    t /= CBN;
    int x  = t % W;      t /= W;
    int y  = t % H;      t /= H;
    int n  = t % NBATCH;
    const float* sb = s_in + ((size_t)n * CIN + sp * CIN_SP) * H * W * TT + tc * 4;
    pf2 acc[4][4][2]; // [cg][c][tt-pair]
#pragma unroll
    for (int a = 0; a < 4; ++a)
#pragma unroll
        for (int b = 0; b < 4; ++b)
#pragma unroll
            for (int d = 0; d < 2; ++d) acc[a][b][d] = (pf2){0.f, 0.f};
#pragma unroll 1
    for (int cl = 0; cl < CIN_SP; ++cl) {
#pragma unroll
        for (int ky = 0; ky < K; ++ky) {
            int yy = y + ky - PAD;
            if (yy < 0 || yy >= H) continue;
#pragma unroll
            for (int kx = 0; kx < K; ++kx) {
                int xx = x + kx - PAD;
                if (xx < 0 || xx >= W) continue;
                float4 v = *(const float4*)(sb + ((size_t)(cl * H + yy) * W + xx) * TT);
                pf2 v01 = {v.x, v.y}, v23 = {v.z, v.w};
                const float* wrow = &wlds[((cl * K + ky) * K + kx) * COUT + cb * 16];
#pragma unroll
                for (int cg = 0; cg < 4; ++cg) {
                    float4 wv = *(const float4*)(wrow + cg * 4);
                    float wa[4] = {wv.x, wv.y, wv.z, wv.w};
#pragma unroll
                    for (int c = 0; c < 4; ++c) {
                        pf2 w2 = {wa[c], wa[c]};
                        acc[cg][c][0] = __builtin_elementwise_fma(w2, v01, acc[cg][c][0]);
                        acc[cg][c][1] = __builtin_elementwise_fma(w2, v23, acc[cg][c][1]);
                    }
                }
            }
        }
    }
    float* zb = z + (((size_t)(sp * NBATCH + n) * COUT + cb * 16) * H * W + (size_t)y * W + x) * TT + tc * 4;
#pragma unroll
    for (int cg = 0; cg < 4; ++cg)
#pragma unroll
        for (int c = 0; c < 4; ++c) {
            float4 o;
            o.x = acc[cg][c][0].x; o.y = acc[cg][c][0].y;
            o.z = acc[cg][c][1].x; o.w = acc[cg][c][1].y;
            *(float4*)(zb + (size_t)(cg * 4 + c) * H * W * TT) = o;
        }
}

// MFMA 3x3 conv (pad 1): spikes {0,1} exact in f16, weights f16 hi/lo split.
template <int CIN, int COUT, int H, int W>
__global__ void __launch_bounds__(256, 2) k_conv_mfma(const float* __restrict__ s_in,
                                                      const _Float16* __restrict__ wm,
                                                      float* __restrict__ z) {
    constexpr int NT = 19;          // ceil(300/16)
    constexpr int KC = CIN / 32;    // K-chunks (of 32 ci) per tap
    constexpr int CH = CIN / 8;     // 16B chunks per t in LDS
    constexpr int XL = W + 2;       // staged x columns (with zero pad)
    constexpr int CT = COUT / 16;   // cout tiles
    constexpr int XPW = W / 4;      // output x per wave
    __shared__ _Float16 lds[3 * XL * 16 * CIN];

    int bid = blockIdx.x;
    int tc = bid % NT;
    int y  = (bid / NT) % H;
    int n  = bid / (NT * H);
    int tid = threadIdx.x;

    constexpr int TOT = 3 * XL * CH * 16;
    for (int i = tid; i < TOT; i += 256) {
        int t   = i & 15;
        int c   = (i >> 4) % CH;
        int xc  = ((i >> 4) / CH) % XL;
        int row = ((i >> 4) / CH) / XL;
        int tg = tc * 16 + t;
        int xi = xc - 1;
        int yi = y + row - 1;
        float v[8] = {0.f, 0.f, 0.f, 0.f, 0.f, 0.f, 0.f, 0.f};
        if (xi >= 0 && xi < W && yi >= 0 && yi < H && tg < TT) {
            const float* p = s_in + (((size_t)(n * CIN + c * 8) * H + yi) * W + xi) * TT + tg;
#pragma unroll
            for (int j = 0; j < 8; ++j) v[j] = p[(size_t)j * H * W * TT];
        }
        h8t hv;
#pragma unroll
        for (int j = 0; j < 8; ++j) hv[j] = (_Float16)v[j];
        int swz = (CIN == 32) ? ((t >> 1) & 3) : (t & 7);   // bank-conflict-free b128 chunks
        int off = ((row * XL + xc) * 16 + t) * CIN + ((c ^ swz) << 3);
        *(h8t*)(lds + off) = hv;
    }
    __syncthreads();

    int lane = tid & 63;
    int wv   = tid >> 6;
    int tl   = lane & 15;
    int hi   = lane >> 4;
    f32x4 acc_h[XPW][CT], acc_l[XPW][CT];
#pragma unroll
    for (int a = 0; a < XPW; ++a)
#pragma unroll
        for (int b = 0; b < CT; ++b) {
            acc_h[a][b] = (f32x4){0.f, 0.f, 0.f, 0.f};
            acc_l[a][b] = (f32x4){0.f, 0.f, 0.f, 0.f};
        }
    const h8t* wmv = (const h8t*)wm;
    int swz = (CIN == 32) ? ((tl >> 1) & 3) : (tl & 7);
#pragma unroll
    for (int ky = 0; ky < 3; ++ky) {
#pragma unroll
        for (int kx = 0; kx < 3; ++kx) {
            int tap = ky * 3 + kx;
#pragma unroll
            for (int kc = 0; kc < KC; ++kc) {
                h8t bf[XPW];   // B-frag: lane supplies B[k = 8*hi + j][n = tl]
#pragma unroll
                for (int xi = 0; xi < XPW; ++xi) {
                    int x = wv * XPW + xi;
                    int c = kc * 4 + hi;
                    int off = ((ky * XL + (x + kx)) * 16 + tl) * CIN + ((c ^ swz) << 3);
                    bf[xi] = *(const h8t*)(lds + off);
                }
#pragma unroll
                for (int ct = 0; ct < CT; ++ct) {
                    size_t wbase = ((size_t)(tap * KC + kc) * CT + ct) * 2;
                    h8t ah = wmv[(wbase + 0) * 64 + lane];
                    h8t al = wmv[(wbase + 1) * 64 + lane];
#pragma unroll
                    for (int xi = 0; xi < XPW; ++xi) {
                        acc_h[xi][ct] = __builtin_amdgcn_mfma_f32_16x16x32_f16(ah, bf[xi], acc_h[xi][ct], 0, 0, 0);
                        acc_l[xi][ct] = __builtin_amdgcn_mfma_f32_16x16x32_f16(al, bf[xi], acc_l[xi][ct], 0, 0, 0);
                    }
                }
            }
        }
    }
    int tg = tc * 16 + tl;
    bool tv = tg < TT;
#pragma unroll
    for (int xi = 0; xi < XPW; ++xi) {
        int x = wv * XPW + xi;
#pragma unroll
        for (int ct = 0; ct < CT; ++ct) {
#pragma unroll
            for (int r = 0; r < 4; ++r) {
                int co = ct * 16 + hi * 4 + r;
                if (tv) z[(((size_t)(n * COUT + co) * H + y) * W + x) * TT + tg]
                        = acc_h[xi][ct][r] + acc_l[xi][ct][r] * 2.44140625e-4f;
            }
        }
    }
}

// MFMA FC: out[n][co][t] = sum_f w[co][f] * s16[n][t][f]. Spikes {0,1} exact in f16,
// weights hi/lo split (exact products, fp32 MFMA accumulate). Block = (cog, n, tc16);
// 4 waves x 1 cout-tile each. K staged 512 features at a time into 16KB LDS with
// XOR-chunk swizzle (same conflict-free pattern as the conv kernel).
template <int FIN, int OUT>
__global__ void __launch_bounds__(256) k_fc_mfma(const _Float16* __restrict__ s16,
                                                 const _Float16* __restrict__ wm,
                                                 float* __restrict__ z) {
    constexpr int NT = 19;          // ceil(300/16)
    constexpr int CT = OUT / 16;    // total cout tiles
    constexpr int KCH = 512;        // features per stage
    constexpr int NK = FIN / KCH;   // stage iterations
    __shared__ _Float16 lds[KCH * 16];   // 16 KB

    int bid = blockIdx.x;           // grid = (CT/4) * NBATCH * NT
    int tc = bid % NT;
    int n  = (bid / NT) % NBATCH;
    int cg = bid / (NT * NBATCH);
    int tid = threadIdx.x;
    int lane = tid & 63, wv = tid >> 6;
    int tl = lane & 15, hi = lane >> 4;
    int ct = cg * 4 + wv;

    f32x4 acc_h = (f32x4){0.f, 0.f, 0.f, 0.f};
    f32x4 acc_l = (f32x4){0.f, 0.f, 0.f, 0.f};
    const h8t* wmv = (const h8t*)wm;

    for (int kb = 0; kb < NK; ++kb) {
        __syncthreads();
        // stage: 512 f x 16 t; chunk = t*64 + c (c = f/8). Writes: 64 lanes hit 64
        // distinct 16B slots (XOR is a permutation within each t row) -> conflict-free.
#pragma unroll
        for (int j = 0; j < 4; ++j) {
            int chunk = tid + j * 256;
            int c = chunk & 63;
            int t = chunk >> 6;
            int tg = tc * 16 + t;
            h8t v;
#pragma unroll
            for (int e = 0; e < 8; ++e) v[e] = (_Float16)0.0f;
            if (tg < TT) v = *(const h8t*)(s16 + ((size_t)(n * TT + tg) * FIN + kb * KCH + c * 8));
            *(h8t*)(lds + ((t * 64 + (c ^ (t & 7))) << 3)) = v;
        }
        __syncthreads();
#pragma unroll
        for (int kc = 0; kc < KCH / 32; ++kc) {
            int c = kc * 4 + hi;
            h8t bf = *(const h8t*)(lds + ((tl * 64 + (c ^ (tl & 7))) << 3));
            size_t wbase = ((size_t)((kb * (KCH / 32) + kc) * CT + ct)) * 2;
            h8t ah = wmv[(wbase + 0) * 64 + lane];
            h8t al = wmv[(wbase + 1) * 64 + lane];
            acc_h = __builtin_amdgcn_mfma_f32_16x16x32_f16(ah, bf, acc_h, 0, 0, 0);
            acc_l = __builtin_amdgcn_mfma_f32_16x16x32_f16(al, bf, acc_l, 0, 0, 0);
        }
    }
    int tg = tc * 16 + tl;
    if (tg < TT) {
#pragma unroll
        for (int r = 0; r < 4; ++r) {
            int co = ct * 16 + hi * 4 + r;
            z[(size_t)(n * OUT + co) * TT + tg] = acc_h[r] + acc_l[r] * 2.44140625e-4f;
        }
    }
}

// FC with f-split, packed fp32 FMA over the t dimension (kept for tiny L7 11x256).
template <int OUT, int FIN, int OPER, int FSPLIT>
__global__ void k_fc_a(const float* __restrict__ s, const float* __restrict__ wgt,
                       float* __restrict__ z) {
    constexpr int OG = OUT / OPER, FCH = FIN / FSPLIT;
    int idx = blockIdx.x * 256 + threadIdx.x;
    if (idx >= NBATCH * OG * TC * FSPLIT) return;
    int tc = idx % TC;
    int og = (idx / TC) % OG;
    int n  = (idx / (TC * OG)) % NBATCH;
    int sp = idx / (TC * OG * NBATCH);
    const float* sb = s + (size_t)n * FIN * TT + (size_t)sp * FCH * TT + tc * 4;
    const float* wb = wgt + (size_t)sp * FCH;
    pf2 acc[OPER][2];
#pragma unroll
    for (int k = 0; k < OPER; ++k) { acc[k][0] = (pf2){0.f, 0.f}; acc[k][1] = (pf2){0.f, 0.f}; }
#pragma unroll 2
    for (int f = 0; f < FCH; f += 4) {
        float4 s0 = *(const float4*)(sb + (size_t)(f + 0) * TT);
        float4 s1 = *(const float4*)(sb + (size_t)(f + 1) * TT);
        float4 s2 = *(const float4*)(sb + (size_t)(f + 2) * TT);
        float4 s3 = *(const float4*)(sb + (size_t)(f + 3) * TT);
        pf2 s0a = {s0.x, s0.y}, s0b = {s0.z, s0.w};
        pf2 s1a = {s1.x, s1.y}, s1b = {s1.z, s1.w};
        pf2 s2a = {s2.x, s2.y}, s2b = {s2.z, s2.w};
        pf2 s3a = {s3.x, s3.y}, s3b = {s3.z, s3.w};
#pragma unroll
        for (int k = 0; k < OPER; ++k) {
            float4 wv = *(const float4*)(wb + (size_t)(og * OPER + k) * FIN + f);
            pf2 wx = {wv.x, wv.x}, wy = {wv.y, wv.y}, wz = {wv.z, wv.z}, ww = {wv.w, wv.w};
            pf2 a0 = acc[k][0], a1 = acc[k][1];
            a0 = __builtin_elementwise_fma(wx, s0a, a0);
            a0 = __builtin_elementwise_fma(wy, s1a, a0);
            a0 = __builtin_elementwise_fma(wz, s2a, a0);
            a0 = __builtin_elementwise_fma(ww, s3a, a0);
            a1 = __builtin_elementwise_fma(wx, s0b, a1);
            a1 = __builtin_elementwise_fma(wy, s1b, a1);
            a1 = __builtin_elementwise_fma(wz, s2b, a1);
            a1 = __builtin_elementwise_fma(ww, s3b, a1);
            acc[k][0] = a0; acc[k][1] = a1;
        }
    }
#pragma unroll
    for (int k = 0; k < OPER; ++k) {
        float4 o;
        o.x = acc[k][0].x; o.y = acc[k][0].y; o.z = acc[k][1].x; o.w = acc[k][1].y;
        *(float4*)(z + ((size_t)sp * NBATCH * OUT + (size_t)n * OUT + og * OPER + k) * TT + tc * 4) = o;
    }
}

extern "C" void kernel_launch(void* const* d_in, const int* in_sizes, int n_in,
                              void* d_out, int out_size, void* d_ws, size_t ws_size,
                              hipStream_t stream) {
    const float* s_in = (const float*)d_in[0]; // (4,2,128,128,300)
    const float* w1   = (const float*)d_in[1]; // (32,2,5,5)
    const float* w2   = (const float*)d_in[2]; // (64,32,3,3)
    const float* w3   = (const float*)d_in[3]; // (64,64,3,3)
    const float* w4a  = (const float*)d_in[4]; // (256,4096)
    const float* w4b  = (const float*)d_in[5]; // (11,256)
    float* out = (float*)d_out;                // (4,11,300)

    // Workspace map (floats): Z 39,321,600 | Sb 9,830,400 | WP 56,896.
    // Inside Z (free at the times they're live):
    //   S16  @ Z+25,000,000 : 4,915,200 halves (f16 spikes [n][t][f], written after L5)
    //   WM4  @ Z+28,000,000 : 2,097,152 halves (packed FC A-frags, written after L1 spsq
    //                         since L1's z1 output occupies all of Z before that)
    float* Z  = (float*)d_ws;
    float* Sb = Z + 39321600;
    float* WP = Sb + 9830400;
    float* w1p = WP;                                     // 50*32 = 1600 floats
    _Float16* wm2 = (_Float16*)(WP + 1600);              // L3 MFMA frags
    _Float16* wm3 = (_Float16*)(WP + 1600 + 18432);      // L5 MFMA frags
    _Float16* S16 = (_Float16*)(Z + 25000000);
    _Float16* wm4 = (_Float16*)(Z + 28000000);

    auto g = [](int n) { return (n + 255) / 256; };
    auto g64 = [](int n) { return (n + 63) / 64; };

    k_pack_w<<<g(1600), 256, 0, stream>>>(w1, w1p, 50, 32, 1600);
    k_pack_wmfma<<<g(4608), 256, 0, stream>>>(w2, wm2, 32, 64, 4608);
    k_pack_wmfma<<<g(9216), 256, 0, stream>>>(w3, wm3, 64, 64, 9216);

    // L0: 4x4 pool + psp -> s0 (4,2,32,32,300) @ Sb
    k_pool4<<<g(614400), 256, 0, stream>>>(s_in, Z);
    k_scan_redp<1><<<g64(8192), 64, 0, stream>>>(Z, Sb, 8192, 0);

    // L1 conv 5x5 (2->32, 32x32) on VALU path: z1 (39.3M) @ Z. 2400 blocks exact.
    k_conv_lds<1, 2, 32, 32, 32, 5, 2><<<2400, 256, 0, stream>>>(Sb, w1p, Z);
    // L1 psp + 2x2 pool + L2 psp -> s2 (4,32,16,16,300) @ Sb. 512 blocks.
    k_spsq<1, 32, 16, 16><<<512, 256, 0, stream>>>(Z, Sb, 0);

    // Z is now free: pack FC weights into Z+28M (128 kg * 16 ct * 2 ver * 64 lanes).
    k_pack_wfc<<<g(262144), 256, 0, stream>>>(w4a, wm4, 4096, 256, 262144);

    // L3 conv 3x3 (32->64, 16x16) MFMA: single-copy z3 (19.66M) @ Z. grid = 4*16*19.
    k_conv_mfma<32, 64, 16, 16><<<1216, 256, 0, stream>>>(Sb, wm2, Z);
    // L3 psp + 2x2 pool + L4 psp -> s4 (4,64,8,8,300) @ Sb. 256 blocks.
    k_spsq<1, 64, 8, 8><<<256, 256, 0, stream>>>(Z, Sb, 0);

    // L5 conv 3x3 (64->64, 8x8) MFMA: single-copy z5 (4.92M) @ Z. grid = 4*8*19.
    k_conv_mfma<64, 64, 8, 8><<<608, 256, 0, stream>>>(Sb, wm3, Z);
    // psp scan -> f16 spikes [n][t][f] @ S16 (16384 neurons).
    k_scan_f16<4096><<<g64(16384), 64, 0, stream>>>(Z, S16, 16384);

    // L6: fc 4096->256 MFMA: z6 (4,256,300) @ Z. grid = 4 cog * 4 n * 19 tc = 304.
    k_fc_mfma<4096, 256><<<304, 256, 0, stream>>>(S16, wm4, Z);
    k_scan_redp<1><<<g64(1024), 64, 0, stream>>>(Z, Sb, 1024, 0);

    // L7: fc 256->11 + psp -> out
    k_fc_a<11, 256, 1, 1><<<g(3300), 256, 0, stream>>>(Sb, w4b, Z);
    k_scan_redp<1><<<1, 64, 0, stream>>>(Z, out, 44, 0);
}

// Round 3
// 638.726 us; speedup vs baseline: 1.2117x; 1.0216x over previous
//
#include <hip/hip_runtime.h>
#include <cstdint>

#define TT 300   // timesteps
#define TC 75    // TT/4
#define NBATCH 4

typedef float pf2 __attribute__((ext_vector_type(2)));   // packs to v_pk_fma_f32
typedef _Float16 h8t __attribute__((ext_vector_type(8)));  // 4 VGPRs = MFMA f16 A/B frag
typedef float f32x4 __attribute__((ext_vector_type(4)));   // MFMA C/D frag

// PSP + refractory IIR step, exact op order of the reference scan.
__device__ __forceinline__ void psp_step(float z, float& gp, float& hp, float& gr, float& hr, float& s_out) {
    hp = 0.90483741803595957f * (hp + gp);      // a_sr = exp(-1/10)
    gp = 0.90483741803595957f * gp + z;
    hr = 0.36787944117144233f * (hr + gr);      // a_rf = exp(-1)
    gr = 0.36787944117144233f * gr;
    float u = 0.27182818284590452f * hp + (-54.365636569180904f) * hr; // c_sr*hp + c_rf*hr
    float s = (u >= 10.0f) ? 1.0f : 0.0f;
    gr += s;
    s_out = s;
}

// Per-neuron scan over T with fused R-way partial reduce, 12-step chunks.
template <int R>
__global__ void k_scan_redp(const float* __restrict__ z, float* __restrict__ s,
                            int n_neur, int pstride) {
    int i = blockIdx.x * 64 + threadIdx.x;
    if (i >= n_neur) return;
    const float* zp = z + (size_t)i * TT;
    float* sp = s + (size_t)i * TT;
    float gp = 0.f, hp = 0.f, gr = 0.f, hr = 0.f;
#pragma unroll 1
    for (int c = 0; c < 25; ++c) {
        const float* p = zp + c * 12;
        float4 a0 = *(const float4*)(p);
        float4 a1 = *(const float4*)(p + 4);
        float4 a2 = *(const float4*)(p + 8);
#pragma unroll
        for (int r = 1; r < R; ++r) {
            const float* pr = p + (size_t)r * pstride;
            float4 b0 = *(const float4*)(pr);
            float4 b1 = *(const float4*)(pr + 4);
            float4 b2 = *(const float4*)(pr + 8);
            a0.x += b0.x; a0.y += b0.y; a0.z += b0.z; a0.w += b0.w;
            a1.x += b1.x; a1.y += b1.y; a1.z += b1.z; a1.w += b1.w;
            a2.x += b2.x; a2.y += b2.y; a2.z += b2.z; a2.w += b2.w;
        }
        float4 o0, o1, o2;
        psp_step(a0.x, gp, hp, gr, hr, o0.x);
        psp_step(a0.y, gp, hp, gr, hr, o0.y);
        psp_step(a0.z, gp, hp, gr, hr, o0.z);
        psp_step(a0.w, gp, hp, gr, hr, o0.w);
        psp_step(a1.x, gp, hp, gr, hr, o1.x);
        psp_step(a1.y, gp, hp, gr, hr, o1.y);
        psp_step(a1.z, gp, hp, gr, hr, o1.z);
        psp_step(a1.w, gp, hp, gr, hr, o1.w);
        psp_step(a2.x, gp, hp, gr, hr, o2.x);
        psp_step(a2.y, gp, hp, gr, hr, o2.y);
        psp_step(a2.z, gp, hp, gr, hr, o2.z);
        psp_step(a2.w, gp, hp, gr, hr, o2.w);
        float* q = sp + c * 12;
        *(float4*)(q) = o0;
        *(float4*)(q + 4) = o1;
        *(float4*)(q + 8) = o2;
    }
}

// Scan variant that writes ONLY a f16 [n][t][f] spike tensor (for the MFMA FC).
template <int FIN>
__global__ void k_scan_f16(const float* __restrict__ z, _Float16* __restrict__ s16,
                           int n_neur) {
    int i = blockIdx.x * 64 + threadIdx.x;
    if (i >= n_neur) return;
    int n = i / FIN, f = i % FIN;
    const float* zp = z + (size_t)i * TT;
    _Float16* sp = s16 + (size_t)n * TT * FIN + f;
    float gp = 0.f, hp = 0.f, gr = 0.f, hr = 0.f;
#pragma unroll 1
    for (int c = 0; c < 25; ++c) {
        const float* p = zp + c * 12;
        float4 a0 = *(const float4*)(p);
        float4 a1 = *(const float4*)(p + 4);
        float4 a2 = *(const float4*)(p + 8);
        float zv[12] = {a0.x, a0.y, a0.z, a0.w, a1.x, a1.y, a1.z, a1.w, a2.x, a2.y, a2.z, a2.w};
#pragma unroll
        for (int tt = 0; tt < 12; ++tt) {
            float o;
            psp_step(zv[tt], gp, hp, gr, hr, o);
            sp[(size_t)(c * 12 + tt) * FIN] = (_Float16)o;
        }
    }
}

// Fused scan-pool-scan emitting f16 spikes in conv-native layout [n][c/8][y2][x2][t][8].
// Thread i: q = i&3 (quad = the 4 conv neurons pooled together, in lane bits 0-1 so
// shfl_xor(1)/(2) pool is exact), then c fastest so a block covers all C channels of
// SPB spatial sites; per 12-t chunk a small LDS tile transposes (c major) -> (t, c8)
// for coalesced 16B global writes.
template <int C, int H2, int W2>
__global__ void __launch_bounds__(256) k_spsq_f16(const float* __restrict__ z,
                                                  _Float16* __restrict__ s16) {
    constexpr int H = 2 * H2, W = 2 * W2;
    constexpr int SPB = (C >= 64) ? 1 : 64 / C;   // spatial sites per 256-thr block
    constexpr int C8 = C / 8;
    __shared__ _Float16 tile[SPB * 12 * C];

    int i = blockIdx.x * 256 + threadIdx.x;       // grid exact: N*C*H2*W2*4 threads
    int q = i & 3;
    int p = i >> 2;
    int c  = p % C;
    int x2 = (p / C) % W2;
    int y2 = (p / (C * W2)) % H2;
    int n  = p / (C * W2 * H2);
    int dy = q >> 1, dx = q & 1;
    const float* zp = z + (((size_t)(n * C + c) * H + 2 * y2 + dy) * W + 2 * x2 + dx) * TT;

    int tid = threadIdx.x;
    int spl = (tid >> 2) / C;                     // this thread's spatial idx in block

    // writer role: tid < SPB*12*C8 writes (wsp, wt, wc8) each chunk
    int wt  = tid % 12;
    int wc8 = (tid / 12) % C8;
    int wsp = tid / (12 * C8);
    bool writer = tid < SPB * 12 * C8;
    int p0 = blockIdx.x * 64;                     // first p of block (C-aligned)
    int pw = p0 + wsp * C;
    int wx2 = (pw / C) % W2;
    int wy2 = (pw / (C * W2)) % H2;
    int wn  = pw / (C * W2 * H2);
    _Float16* wbase = s16 + ((((size_t)(wn * C8 + wc8) * H2 + wy2) * W2 + wx2) * TT) * 8;

    float gp = 0.f, hp = 0.f, gr = 0.f, hr = 0.f;   // conv neuron IIR
    float Gp = 0.f, Hp = 0.f, Gr = 0.f, Hr = 0.f;   // pooled neuron IIR
#pragma unroll 1
    for (int cc = 0; cc < 25; ++cc) {
        const float* pp = zp + cc * 12;
        float4 a0 = *(const float4*)(pp);
        float4 a1 = *(const float4*)(pp + 4);
        float4 a2 = *(const float4*)(pp + 8);
        float zv[12] = {a0.x, a0.y, a0.z, a0.w, a1.x, a1.y, a1.z, a1.w, a2.x, a2.y, a2.z, a2.w};
        float ov[12];
#pragma unroll
        for (int tt = 0; tt < 12; ++tt) {
            float sq;
            psp_step(zv[tt], gp, hp, gr, hr, sq);
            float t1 = sq + __shfl_xor(sq, 1, 64);
            float pool = t1 + __shfl_xor(t1, 2, 64);
            psp_step(11.0f * pool, Gp, Hp, Gr, Hr, ov[tt]);
        }
        __syncthreads();   // previous chunk's writers done with tile
        if (q == 0) {
#pragma unroll
            for (int tt = 0; tt < 12; ++tt)
                tile[(spl * 12 + tt) * C + c] = (_Float16)ov[tt];
        }
        __syncthreads();
        if (writer) {
            h8t v;
#pragma unroll
            for (int e = 0; e < 8; ++e) v[e] = tile[(wsp * 12 + wt) * C + wc8 * 8 + e];
            *(h8t*)(wbase + (size_t)(cc * 12 + wt) * 8) = v;
        }
    }
}

// Transpose-pack OIHW weights (COUT, S) -> [s][COUT] so one tap's weights are contiguous.
__global__ void k_pack_w(const float* __restrict__ w, float* __restrict__ wp, int S, int CO, int total) {
    int i = blockIdx.x * 256 + threadIdx.x;
    if (i >= total) return;
    int co = i % CO, s = i / CO;
    wp[i] = w[co * S + s];
}

// Pack 3x3 OIHW conv weights into MFMA A-fragments with f16 hi/lo split:
//   w == hi + lo * 2^-12  (lo pre-scaled by 2^12; spikes are {0,1} so products exact).
// Layout: [tap 9][kc CIN/32][ct COUT/16][ver 2][lane 64][j 8] halves.
// A-frag convention: lane supplies A[m = lane&15][k = 8*(lane>>4) + j], m = cout, k = ci.
__global__ void k_pack_wmfma(const float* __restrict__ w, _Float16* __restrict__ wm,
                             int CIN, int COUT, int total) {
    int i = blockIdx.x * 256 + threadIdx.x;
    if (i >= total) return;
    int lane = i & 63;
    int r = i >> 6;
    int ver = r & 1; r >>= 1;
    int KC = CIN >> 5, CT = COUT >> 4;
    int ct = r % CT; r /= CT;
    int kc = r % KC;
    int tap = r / KC;
    int ky = tap / 3, kx = tap % 3;
    int co  = ct * 16 + (lane & 15);
    int ci0 = kc * 32 + (lane >> 4) * 8;
    _Float16 out[8];
#pragma unroll
    for (int j = 0; j < 8; ++j) {
        float wf = w[((co * CIN + ci0 + j) * 3 + ky) * 3 + kx];
        _Float16 hi = (_Float16)wf;
        out[j] = ver ? (_Float16)((wf - (float)hi) * 4096.0f) : hi;
    }
    *(h8t*)(wm + (size_t)i * 8) = *(h8t*)out;
}

// Pack FC weights (COUT, FIN) row-major into MFMA A-fragments, hi/lo split.
// Layout: [kg FIN/32][ct COUT/16][ver 2][lane 64][j 8] halves.
__global__ void k_pack_wfc(const float* __restrict__ w, _Float16* __restrict__ wm,
                           int FIN, int COUT, int total) {
    int i = blockIdx.x * 256 + threadIdx.x;
    if (i >= total) return;
    int lane = i & 63;
    int r = i >> 6;
    int ver = r & 1; r >>= 1;
    int CT = COUT >> 4;
    int ct = r % CT;
    int kg = r / CT;
    int co = ct * 16 + (lane & 15);
    int f0 = kg * 32 + (lane >> 4) * 8;
    _Float16 out[8];
#pragma unroll
    for (int j = 0; j < 8; ++j) {
        float wf = w[(size_t)co * FIN + f0 + j];
        _Float16 hi = (_Float16)wf;
        out[j] = ver ? (_Float16)((wf - (float)hi) * 4096.0f) : hi;
    }
    *(h8t*)(wm + (size_t)i * 8) = *(h8t*)out;
}

// 4x4 sum-pool * 11.0 over (N,2,128,128,T) -> z (N,2,32,32,T). Thread = (p, tc), tc fastest.
__global__ void k_pool4(const float* __restrict__ x, float* __restrict__ z) {
    int idx = blockIdx.x * 256 + threadIdx.x;
    if (idx >= NBATCH * 2 * 32 * 32 * TC) return;
    int tc = idx % TC;
    int p  = idx / TC;
    int w  = p % 32;
    int h  = (p / 32) % 32;
    int nc = p / (32 * 32);
    const float* base = x + (((size_t)nc * 128 + h * 4) * 128 + w * 4) * TT + tc * 4;
    float ax = 0.f, ay = 0.f, az = 0.f, aw = 0.f;
#pragma unroll
    for (int i = 0; i < 4; ++i)
#pragma unroll
        for (int j = 0; j < 4; ++j) {
            float4 v = *(const float4*)(base + ((size_t)i * 128 + j) * TT);
            ax += v.x; ay += v.y; az += v.z; aw += v.w;
        }
    float4 o; o.x = 11.0f * ax; o.y = 11.0f * ay; o.z = 11.0f * az; o.w = 11.0f * aw;
    *(float4*)(z + (size_t)p * TT + tc * 4) = o;
}

// LDS-weight conv with packed fp32 FMA (kept for L1 5x5 CIN=2, which is MFMA-awkward).
template <int SPLIT, int CIN, int COUT, int H, int W, int K, int PAD>
__global__ void __launch_bounds__(256) k_conv_lds(const float* __restrict__ s_in,
                                                  const float* __restrict__ wp,
                                                  float* __restrict__ z) {
    constexpr int CBN = COUT / 16;
    constexpr int CIN_SP = CIN / SPLIT;
    constexpr int S_SP = CIN_SP * K * K;
    __shared__ float wlds[S_SP * COUT];
    int nb8 = gridDim.x >> 3;
    int lb  = (blockIdx.x >> 3) + (blockIdx.x & 7) * nb8;
    int sp = (int)(((size_t)lb * 256) / (CBN * NBATCH * H * W * TC));
    {
        const float4* src = (const float4*)(wp + (size_t)sp * S_SP * COUT);
        float4* dst = (float4*)wlds;
        for (int i = threadIdx.x; i < S_SP * COUT / 4; i += 256) dst[i] = src[i];
    }
    __syncthreads();
    int t = lb * 256 + threadIdx.x;
    int tc = t % TC;     t /= TC;
    int cb = t % CBN;    t /= CBN;
    int x  = t % W;      t /= W;
    int y  = t % H;      t /= H;
    int n  = t % NBATCH;
    const float* sb = s_in + ((size_t)n * CIN + sp * CIN_SP) * H * W * TT + tc * 4;
    pf2 acc[4][4][2]; // [cg][c][tt-pair]
#pragma unroll
    for (int a = 0; a < 4; ++a)
#pragma unroll
        for (int b = 0; b < 4; ++b)
#pragma unroll
            for (int d = 0; d < 2; ++d) acc[a][b][d] = (pf2){0.f, 0.f};
#pragma unroll 1
    for (int cl = 0; cl < CIN_SP; ++cl) {
#pragma unroll
        for (int ky = 0; ky < K; ++ky) {
            int yy = y + ky - PAD;
            if (yy < 0 || yy >= H) continue;
#pragma unroll
            for (int kx = 0; kx < K; ++kx) {
                int xx = x + kx - PAD;
                if (xx < 0 || xx >= W) continue;
                float4 v = *(const float4*)(sb + ((size_t)(cl * H + yy) * W + xx) * TT);
                pf2 v01 = {v.x, v.y}, v23 = {v.z, v.w};
                const float* wrow = &wlds[((cl * K + ky) * K + kx) * COUT + cb * 16];
#pragma unroll
                for (int cg = 0; cg < 4; ++cg) {
                    float4 wv = *(const float4*)(wrow + cg * 4);
                    float wa[4] = {wv.x, wv.y, wv.z, wv.w};
#pragma unroll
                    for (int c = 0; c < 4; ++c) {
                        pf2 w2 = {wa[c], wa[c]};
                        acc[cg][c][0] = __builtin_elementwise_fma(w2, v01, acc[cg][c][0]);
                        acc[cg][c][1] = __builtin_elementwise_fma(w2, v23, acc[cg][c][1]);
                    }
                }
            }
        }
    }
    float* zb = z + (((size_t)(sp * NBATCH + n) * COUT + cb * 16) * H * W + (size_t)y * W + x) * TT + tc * 4;
#pragma unroll
    for (int cg = 0; cg < 4; ++cg)
#pragma unroll
        for (int c = 0; c < 4; ++c) {
            float4 o;
            o.x = acc[cg][c][0].x; o.y = acc[cg][c][0].y;
            o.z = acc[cg][c][1].x; o.w = acc[cg][c][1].y;
            *(float4*)(zb + (size_t)(cg * 4 + c) * H * W * TT) = o;
        }
}

// MFMA 3x3 conv (pad 1). Input: f16 spikes [n][ci/8][y][x][t][8] (conv-native layout:
// staging = one contiguous h8t load per item, 256B/16-lane segments). YPB output rows
// per block: stages YPB+2 rows, cutting the y-halo refetch (3x -> (YPB+2)/YPB).
// Weights f16 hi/lo split (exact on {0,1} spikes); fp32 MFMA accumulate.
template <int CIN, int COUT, int H, int W, int YPB>
__global__ void __launch_bounds__(256, 2) k_conv_mfma(const _Float16* __restrict__ s16,
                                                      const _Float16* __restrict__ wm,
                                                      float* __restrict__ z) {
    constexpr int NT = 19;          // ceil(300/16)
    constexpr int KC = CIN / 32;    // K-chunks (of 32 ci) per tap
    constexpr int CH = CIN / 8;     // 16B chunks per t
    constexpr int XL = W + 2;       // staged x columns (with zero pad)
    constexpr int CT = COUT / 16;   // cout tiles
    constexpr int XPW = W / 4;      // output x per wave
    constexpr int ROWS = YPB + 2;
    __shared__ _Float16 lds[ROWS * XL * 16 * CIN];

    int bid = blockIdx.x;
    int tc = bid % NT;
    int yb = ((bid / NT) % (H / YPB)) * YPB;
    int n  = bid / (NT * (H / YPB));
    int tid = threadIdx.x;

    constexpr int TOT = ROWS * XL * CH * 16;   // h8t items
    for (int i = tid; i < TOT; i += 256) {
        int t   = i & 15;
        int c   = (i >> 4) % CH;
        int xc  = ((i >> 4) / CH) % XL;
        int row = ((i >> 4) / CH) / XL;
        int tg = tc * 16 + t;
        int xi = xc - 1;
        int yi = yb + row - 1;
        h8t v;
#pragma unroll
        for (int e = 0; e < 8; ++e) v[e] = (_Float16)0.0f;
        if (xi >= 0 && xi < W && yi >= 0 && yi < H && tg < TT)
            v = *(const h8t*)(s16 + ((((size_t)(n * CH + c) * H + yi) * W + xi) * TT + tg) * 8);
        int swz = (CIN == 32) ? ((t >> 1) & 3) : (t & 7);   // bank-conflict-free b128 chunks
        int off = ((row * XL + xc) * 16 + t) * CIN + ((c ^ swz) << 3);
        *(h8t*)(lds + off) = v;
    }
    __syncthreads();

    int lane = tid & 63;
    int wv   = tid >> 6;
    int tl   = lane & 15;
    int hi   = lane >> 4;
    const h8t* wmv = (const h8t*)wm;
    int swz = (CIN == 32) ? ((tl >> 1) & 3) : (tl & 7);
    int tg = tc * 16 + tl;
    bool tv = tg < TT;

#pragma unroll
    for (int yy = 0; yy < YPB; ++yy) {
        f32x4 acc_h[XPW][CT], acc_l[XPW][CT];
#pragma unroll
        for (int a = 0; a < XPW; ++a)
#pragma unroll
            for (int b = 0; b < CT; ++b) {
                acc_h[a][b] = (f32x4){0.f, 0.f, 0.f, 0.f};
                acc_l[a][b] = (f32x4){0.f, 0.f, 0.f, 0.f};
            }
#pragma unroll
        for (int ky = 0; ky < 3; ++ky) {
#pragma unroll
            for (int kx = 0; kx < 3; ++kx) {
                int tap = ky * 3 + kx;
#pragma unroll
                for (int kc = 0; kc < KC; ++kc) {
                    h8t bf[XPW];   // B-frag: lane supplies B[k = 8*hi + j][col = tl]
#pragma unroll
                    for (int xi = 0; xi < XPW; ++xi) {
                        int x = wv * XPW + xi;
                        int c = kc * 4 + hi;
                        int off = (((yy + ky) * XL + (x + kx)) * 16 + tl) * CIN + ((c ^ swz) << 3);
                        bf[xi] = *(const h8t*)(lds + off);
                    }
#pragma unroll
                    for (int ct = 0; ct < CT; ++ct) {
                        size_t wbase = ((size_t)(tap * KC + kc) * CT + ct) * 2;
                        h8t ah = wmv[(wbase + 0) * 64 + lane];
                        h8t al = wmv[(wbase + 1) * 64 + lane];
#pragma unroll
                        for (int xi = 0; xi < XPW; ++xi) {
                            acc_h[xi][ct] = __builtin_amdgcn_mfma_f32_16x16x32_f16(ah, bf[xi], acc_h[xi][ct], 0, 0, 0);
                            acc_l[xi][ct] = __builtin_amdgcn_mfma_f32_16x16x32_f16(al, bf[xi], acc_l[xi][ct], 0, 0, 0);
                        }
                    }
                }
            }
        }
        // C/D layout: col = lane&15 (= t), row = (lane>>4)*4 + r (= cout)
#pragma unroll
        for (int xi = 0; xi < XPW; ++xi) {
            int x = wv * XPW + xi;
#pragma unroll
            for (int ct = 0; ct < CT; ++ct) {
#pragma unroll
                for (int r = 0; r < 4; ++r) {
                    int co = ct * 16 + hi * 4 + r;
                    if (tv) z[(((size_t)(n * COUT + co) * H + (yb + yy)) * W + x) * TT + tg]
                            = acc_h[xi][ct][r] + acc_l[xi][ct][r] * 2.44140625e-4f;
                }
            }
        }
    }
}

// MFMA FC: out[n][co][t] = sum_f w[co][f] * s16[n][t][f].
template <int FIN, int OUT>
__global__ void __launch_bounds__(256) k_fc_mfma(const _Float16* __restrict__ s16,
                                                 const _Float16* __restrict__ wm,
                                                 float* __restrict__ z) {
    constexpr int NT = 19;          // ceil(300/16)
    constexpr int CT = OUT / 16;    // total cout tiles
    constexpr int KCH = 512;        // features per stage
    constexpr int NK = FIN / KCH;   // stage iterations
    __shared__ _Float16 lds[KCH * 16];   // 16 KB

    int bid = blockIdx.x;           // grid = (CT/4) * NBATCH * NT
    int tc = bid % NT;
    int n  = (bid / NT) % NBATCH;
    int cg = bid / (NT * NBATCH);
    int tid = threadIdx.x;
    int lane = tid & 63, wv = tid >> 6;
    int tl = lane & 15, hi = lane >> 4;
    int ct = cg * 4 + wv;

    f32x4 acc_h = (f32x4){0.f, 0.f, 0.f, 0.f};
    f32x4 acc_l = (f32x4){0.f, 0.f, 0.f, 0.f};
    const h8t* wmv = (const h8t*)wm;

    for (int kb = 0; kb < NK; ++kb) {
        __syncthreads();
#pragma unroll
        for (int j = 0; j < 4; ++j) {
            int chunk = tid + j * 256;
            int c = chunk & 63;
            int t = chunk >> 6;
            int tg = tc * 16 + t;
            h8t v;
#pragma unroll
            for (int e = 0; e < 8; ++e) v[e] = (_Float16)0.0f;
            if (tg < TT) v = *(const h8t*)(s16 + ((size_t)(n * TT + tg) * FIN + kb * KCH + c * 8));
            *(h8t*)(lds + ((t * 64 + (c ^ (t & 7))) << 3)) = v;
        }
        __syncthreads();
#pragma unroll
        for (int kc = 0; kc < KCH / 32; ++kc) {
            int c = kc * 4 + hi;
            h8t bf = *(const h8t*)(lds + ((tl * 64 + (c ^ (tl & 7))) << 3));
            size_t wbase = ((size_t)((kb * (KCH / 32) + kc) * CT + ct)) * 2;
            h8t ah = wmv[(wbase + 0) * 64 + lane];
            h8t al = wmv[(wbase + 1) * 64 + lane];
            acc_h = __builtin_amdgcn_mfma_f32_16x16x32_f16(ah, bf, acc_h, 0, 0, 0);
            acc_l = __builtin_amdgcn_mfma_f32_16x16x32_f16(al, bf, acc_l, 0, 0, 0);
        }
    }
    int tg = tc * 16 + tl;
    if (tg < TT) {
#pragma unroll
        for (int r = 0; r < 4; ++r) {
            int co = ct * 16 + hi * 4 + r;
            z[(size_t)(n * OUT + co) * TT + tg] = acc_h[r] + acc_l[r] * 2.44140625e-4f;
        }
    }
}

// FC with f-split, packed fp32 FMA over the t dimension (kept for tiny L7 11x256).
template <int OUT, int FIN, int OPER, int FSPLIT>
__global__ void k_fc_a(const float* __restrict__ s, const float* __restrict__ wgt,
                       float* __restrict__ z) {
    constexpr int OG = OUT / OPER, FCH = FIN / FSPLIT;
    int idx = blockIdx.x * 256 + threadIdx.x;
    if (idx >= NBATCH * OG * TC * FSPLIT) return;
    int tc = idx % TC;
    int og = (idx / TC) % OG;
    int n  = (idx / (TC * OG)) % NBATCH;
    int sp = idx / (TC * OG * NBATCH);
    const float* sb = s + (size_t)n * FIN * TT + (size_t)sp * FCH * TT + tc * 4;
    const float* wb = wgt + (size_t)sp * FCH;
    pf2 acc[OPER][2];
#pragma unroll
    for (int k = 0; k < OPER; ++k) { acc[k][0] = (pf2){0.f, 0.f}; acc[k][1] = (pf2){0.f, 0.f}; }
#pragma unroll 2
    for (int f = 0; f < FCH; f += 4) {
        float4 s0 = *(const float4*)(sb + (size_t)(f + 0) * TT);
        float4 s1 = *(const float4*)(sb + (size_t)(f + 1) * TT);
        float4 s2 = *(const float4*)(sb + (size_t)(f + 2) * TT);
        float4 s3 = *(const float4*)(sb + (size_t)(f + 3) * TT);
        pf2 s0a = {s0.x, s0.y}, s0b = {s0.z, s0.w};
        pf2 s1a = {s1.x, s1.y}, s1b = {s1.z, s1.w};
        pf2 s2a = {s2.x, s2.y}, s2b = {s2.z, s2.w};
        pf2 s3a = {s3.x, s3.y}, s3b = {s3.z, s3.w};
#pragma unroll
        for (int k = 0; k < OPER; ++k) {
            float4 wv = *(const float4*)(wb + (size_t)(og * OPER + k) * FIN + f);
            pf2 wx = {wv.x, wv.x}, wy = {wv.y, wv.y}, wz = {wv.z, wv.z}, ww = {wv.w, wv.w};
            pf2 a0 = acc[k][0], a1 = acc[k][1];
            a0 = __builtin_elementwise_fma(wx, s0a, a0);
            a0 = __builtin_elementwise_fma(wy, s1a, a0);
            a0 = __builtin_elementwise_fma(wz, s2a, a0);
            a0 = __builtin_elementwise_fma(ww, s3a, a0);
            a1 = __builtin_elementwise_fma(wx, s0b, a1);
            a1 = __builtin_elementwise_fma(wy, s1b, a1);
            a1 = __builtin_elementwise_fma(wz, s2b, a1);
            a1 = __builtin_elementwise_fma(ww, s3b, a1);
            acc[k][0] = a0; acc[k][1] = a1;
        }
    }
#pragma unroll
    for (int k = 0; k < OPER; ++k) {
        float4 o;
        o.x = acc[k][0].x; o.y = acc[k][0].y; o.z = acc[k][1].x; o.w = acc[k][1].y;
        *(float4*)(z + ((size_t)sp * NBATCH * OUT + (size_t)n * OUT + og * OPER + k) * TT + tc * 4) = o;
    }
}

extern "C" void kernel_launch(void* const* d_in, const int* in_sizes, int n_in,
                              void* d_out, int out_size, void* d_ws, size_t ws_size,
                              hipStream_t stream) {
    const float* s_in = (const float*)d_in[0]; // (4,2,128,128,300)
    const float* w1   = (const float*)d_in[1]; // (32,2,5,5)
    const float* w2   = (const float*)d_in[2]; // (64,32,3,3)
    const float* w3   = (const float*)d_in[3]; // (64,64,3,3)
    const float* w4a  = (const float*)d_in[4]; // (256,4096)
    const float* w4b  = (const float*)d_in[5]; // (11,256)
    float* out = (float*)d_out;                // (4,11,300)

    // Workspace map (floats): Z 39,321,600 | Sb 9,830,400 | WP 56,896.
    // Inside Z: S16 @ Z+25M (f16 [n][t][f] spikes), WM4 @ Z+28M (packed FC A-frags).
    // Inside Sb: s0 f32 [0..2.46M) -> dead after conv L1; s2h f16 @ Sb (4.92M floats);
    //            s4h f16 @ Sb+5M (2.46M floats) -> all sequential, no live overlap.
    float* Z  = (float*)d_ws;
    float* Sb = Z + 39321600;
    float* WP = Sb + 9830400;
    float* w1p = WP;                                     // 50*32 = 1600 floats
    _Float16* wm2 = (_Float16*)(WP + 1600);              // L3 MFMA frags
    _Float16* wm3 = (_Float16*)(WP + 1600 + 18432);      // L5 MFMA frags
    _Float16* S16 = (_Float16*)(Z + 25000000);
    _Float16* wm4 = (_Float16*)(Z + 28000000);
    _Float16* s2h = (_Float16*)Sb;                       // f16 [n][4][16][16][300][8]
    _Float16* s4h = (_Float16*)(Sb + 5000000);           // f16 [n][8][8][8][300][8]

    auto g = [](int n) { return (n + 255) / 256; };
    auto g64 = [](int n) { return (n + 63) / 64; };

    k_pack_w<<<g(1600), 256, 0, stream>>>(w1, w1p, 50, 32, 1600);
    k_pack_wmfma<<<g(4608), 256, 0, stream>>>(w2, wm2, 32, 64, 4608);
    k_pack_wmfma<<<g(9216), 256, 0, stream>>>(w3, wm3, 64, 64, 9216);

    // L0: 4x4 pool + psp -> s0 (4,2,32,32,300) f32 @ Sb
    k_pool4<<<g(614400), 256, 0, stream>>>(s_in, Z);
    k_scan_redp<1><<<g64(8192), 64, 0, stream>>>(Z, Sb, 8192, 0);

    // L1 conv 5x5 (2->32, 32x32) on VALU path: z1 (39.3M) @ Z. 2400 blocks exact.
    k_conv_lds<1, 2, 32, 32, 32, 5, 2><<<2400, 256, 0, stream>>>(Sb, w1p, Z);
    // L1 psp + 2x2 pool + L2 psp -> s2h f16 conv-native @ Sb. 512 blocks.
    k_spsq_f16<32, 16, 16><<<512, 256, 0, stream>>>(Z, s2h);

    // Z free: pack FC weights into Z+28M.
    k_pack_wfc<<<g(262144), 256, 0, stream>>>(w4a, wm4, 4096, 256, 262144);

    // L3 conv 3x3 (32->64, 16x16) MFMA, y-pair blocks: z3 (19.66M) @ Z. grid 4*8*19.
    k_conv_mfma<32, 64, 16, 16, 2><<<608, 256, 0, stream>>>(s2h, wm2, Z);
    // L3 psp + 2x2 pool + L4 psp -> s4h f16 conv-native @ Sb+5M. 256 blocks.
    k_spsq_f16<64, 8, 8><<<256, 256, 0, stream>>>(Z, s4h);

    // L5 conv 3x3 (64->64, 8x8) MFMA: z5 (4.92M) @ Z. grid 4*8*19.
    k_conv_mfma<64, 64, 8, 8, 1><<<608, 256, 0, stream>>>(s4h, wm3, Z);
    // psp scan -> f16 spikes [n][t][f] @ S16 (16384 neurons).
    k_scan_f16<4096><<<g64(16384), 64, 0, stream>>>(Z, S16, 16384);

    // L6: fc 4096->256 MFMA: z6 (4,256,300) @ Z. grid = 4 cog * 4 n * 19 tc = 304.
    k_fc_mfma<4096, 256><<<304, 256, 0, stream>>>(S16, wm4, Z);
    k_scan_redp<1><<<g64(1024), 64, 0, stream>>>(Z, Sb, 1024, 0);

    // L7: fc 256->11 + psp -> out
    k_fc_a<11, 256, 1, 1><<<g(3300), 256, 0, stream>>>(Sb, w4b, Z);
    k_scan_redp<1><<<1, 64, 0, stream>>>(Z, out, 44, 0);
}